// Round 11
// baseline (254.386 us; speedup 1.0000x reference)
//
#include <hip/hip_runtime.h>
#include <hip/hip_bf16.h>
#include <float.h>
#include <math.h>

// Problem constants
#define BB 4
#define NN 2048
#define MM 256
#define DIN 1024
#define INNER 1024
#define NHEADS 16
#define DHEAD 64

typedef __attribute__((ext_vector_type(8))) short bf16x8;
typedef __attribute__((ext_vector_type(4))) float f32x4;
typedef __attribute__((ext_vector_type(4))) unsigned int u32x4;

// round-to-nearest-even f32 -> bf16 bit pattern
__device__ __forceinline__ unsigned short f2bf(float f) {
    unsigned int u = __builtin_bit_cast(unsigned int, f);
    u = (u + 0x7fffu + ((u >> 16) & 1u)) >> 16;
    return (unsigned short)u;
}

// raw v_exp_f32 (2^x)
__device__ __forceinline__ float fexp2(float x) {
#if __has_builtin(__builtin_amdgcn_exp2f)
    return __builtin_amdgcn_exp2f(x);
#else
    float r; asm("v_exp_f32 %0, %1" : "=v"(r) : "v"(x)); return r;
#endif
}

// v_cvt_pk_bf16_f32: lo16 = bf16(a), hi16 = bf16(b)  (T12 recipe)
__device__ __forceinline__ unsigned int cvt_pk_bf16(float a, float b) {
    unsigned int r;
    asm("v_cvt_pk_bf16_f32 %0, %1, %2" : "=v"(r) : "v"(a), "v"(b));
    return r;
}

// async global->LDS, 16B per lane; LDS dest = wave-uniform base.
__device__ __forceinline__ void gload_lds16(const void* g, void* l) {
    __builtin_amdgcn_global_load_lds((__attribute__((address_space(1))) void*)(g),
                                     (__attribute__((address_space(3))) void*)(l),
                                     16, 0, 0);
}

#define LOG2E 1.4426950408889634f

// ---------------------------------------------------------------------------
// Fused LayerNorm: rows [0,8192) = x -> xnb ; [8192,10240) = lc1|lc0 -> latb.
// ---------------------------------------------------------------------------
__global__ __launch_bounds__(256) void ln_all_kernel(const float* __restrict__ x,
                                                     const float* __restrict__ lc1,
                                                     const float* __restrict__ lc0,
                                                     unsigned short* __restrict__ xnb,
                                                     unsigned short* __restrict__ latb,
                                                     const float* __restrict__ xw,
                                                     const float* __restrict__ xb,
                                                     const float* __restrict__ lw,
                                                     const float* __restrict__ lb) {
    const int row = blockIdx.x;
    const float* srow;
    unsigned short* drow;
    const float *w, *bv;
    if (row < BB * NN) {
        srow = x + (size_t)row * 1024; drow = xnb + (size_t)row * 1024;
        w = xw; bv = xb;
    } else {
        const int r2 = row - BB * NN;
        srow = (r2 < BB * MM) ? (lc1 + (size_t)r2 * 1024)
                              : (lc0 + (size_t)(r2 - BB * MM) * 1024);
        drow = latb + (size_t)r2 * 1024;
        w = lw; bv = lb;
    }
    const int tid = threadIdx.x;
    const float4 v = ((const float4*)srow)[tid];
    float sum = v.x + v.y + v.z + v.w;
    float sq  = v.x * v.x + v.y * v.y + v.z * v.z + v.w * v.w;
    #pragma unroll
    for (int off = 32; off; off >>= 1) {
        sum += __shfl_down(sum, off);
        sq  += __shfl_down(sq, off);
    }
    __shared__ float ls[4], lq[4];
    const int wv = tid >> 6;
    if ((tid & 63) == 0) { ls[wv] = sum; lq[wv] = sq; }
    __syncthreads();
    sum = ls[0] + ls[1] + ls[2] + ls[3];
    sq  = lq[0] + lq[1] + lq[2] + lq[3];
    const float mu  = sum * (1.0f / 1024.0f);
    const float var = sq * (1.0f / 1024.0f) - mu * mu;
    const float rs  = rsqrtf(var + 1e-5f);
    const float4 w4 = ((const float4*)w)[tid];
    const float4 b4 = ((const float4*)bv)[tid];
    ushort4 o;
    o.x = f2bf((v.x - mu) * rs * w4.x + b4.x);
    o.y = f2bf((v.y - mu) * rs * w4.y + b4.y);
    o.z = f2bf((v.z - mu) * rs * w4.z + b4.z);
    o.w = f2bf((v.w - mu) * rs * w4.w + b4.w);
    ((ushort4*)drow)[tid] = o;
}

// ---------------------------------------------------------------------------
// Fused weight transpose + cast: z=0 Wkv(1024x2048), z=1 Wq, z=2 Wout.
// ---------------------------------------------------------------------------
__global__ __launch_bounds__(256) void transpose_all_kernel(const float* __restrict__ Wkv,
                                                            const float* __restrict__ Wq,
                                                            const float* __restrict__ Wout,
                                                            unsigned short* __restrict__ WkvT,
                                                            unsigned short* __restrict__ WqT,
                                                            unsigned short* __restrict__ WoutT) {
    const int z = blockIdx.z;
    const float* W;
    unsigned short* WT;
    int N;
    if (z == 0)      { W = Wkv;  WT = WkvT;  N = 2048; }
    else if (z == 1) { W = Wq;   WT = WqT;   N = 1024; }
    else             { W = Wout; WT = WoutT; N = 1024; }
    if (blockIdx.x * 32 >= N) return;
    const int K = 1024;
    __shared__ float t[32][33];
    const int k0 = blockIdx.y * 32, n0 = blockIdx.x * 32;
    const int tx = threadIdx.x & 31, ty8 = threadIdx.x >> 5;
    #pragma unroll
    for (int i = 0; i < 4; i++) {
        const int k = ty8 + i * 8;
        t[k][tx] = W[(size_t)(k0 + k) * N + n0 + tx];
    }
    __syncthreads();
    #pragma unroll
    for (int i = 0; i < 4; i++) {
        const int n = ty8 + i * 8;
        WT[(size_t)(n0 + n) * K + k0 + tx] = f2bf(t[tx][n]);
    }
}

// ---------------------------------------------------------------------------
// V transpose (bf16->bf16): vbh[b*N+n][h*64+d] -> vth[(b*16+h)*64+d][n (2048)]
// ---------------------------------------------------------------------------
__global__ __launch_bounds__(256) void v_transpose_bf16(const unsigned short* __restrict__ vbh,
                                                        unsigned short* __restrict__ vth) {
    __shared__ unsigned short t[32][34];
    const int n0 = blockIdx.x * 32;
    const int d0 = blockIdx.y * 32;
    const int bh = blockIdx.z;
    const int b = bh >> 4, h = bh & 15;
    const int tx = threadIdx.x & 31, ty8 = threadIdx.x >> 5;
    #pragma unroll
    for (int i = 0; i < 4; i++) {
        const int nr = ty8 + i * 8;
        t[nr][tx] = vbh[(size_t)(b * NN + n0 + nr) * 1024 + h * 64 + d0 + tx];
    }
    __syncthreads();
    #pragma unroll
    for (int i = 0; i < 4; i++) {
        const int dr = ty8 + i * 8;
        vth[((size_t)(b * 16 + h) * 64 + d0 + dr) * 2048 + n0 + tx] = t[tx][dr];
    }
}

// ---------------------------------------------------------------------------
// bf16 MFMA GEMM, BMxBN tile, BK=32, double-buffered 2-phase (round-6 measured
// structure), XCD-swizzled (T1). 4 waves; NWC=BN/64 col-waves x NWR row-waves.
// MODE 0: C f32 (+bias aux).
// MODE 1: kv -> K half rms-normed*gamma_k -> outK bf16 ; V half -> outV bf16.
// MODE 2: q  -> rms-normed*gamma_q*SCALE*log2e -> outK bf16.
// Requires K % 64 == 0, grid count % 8 == 0.
// ---------------------------------------------------------------------------
#define GEMM_STAGE(AS, BS, kt)                                                        \
    {                                                                                 \
        _Pragma("unroll")                                                             \
        for (int e = 0; e < EA; e++) {                                                \
            const int r0 = (w * EA + e) * 16;                                         \
            gload_lds16(Ag + (size_t)(r0 + srow) * K + (kt) + selt, &AS[r0 * 32]);    \
        }                                                                             \
        _Pragma("unroll")                                                             \
        for (int e = 0; e < EB; e++) {                                                \
            const int r0 = (w * EB + e) * 16;                                         \
            gload_lds16(Bg + (size_t)(r0 + srow) * K + (kt) + selt, &BS[r0 * 32]);    \
        }                                                                             \
    }

#define GEMM_COMPUTE(AS, BS)                                                          \
    {                                                                                 \
        bf16x8 af[MREP], bfv[4];                                                      \
        _Pragma("unroll")                                                             \
        for (int m = 0; m < MREP; m++)                                                \
            af[m] = *(const bf16x8*)&AS[(wr * WROWS + m * 16 + (l & 15)) * 32 + (l >> 4) * 8]; \
        _Pragma("unroll")                                                             \
        for (int n = 0; n < 4; n++)                                                   \
            bfv[n] = *(const bf16x8*)&BS[(wc * 64 + n * 16 + (l & 15)) * 32 + (l >> 4) * 8]; \
        _Pragma("unroll")                                                             \
        for (int m = 0; m < MREP; m++)                                                \
            _Pragma("unroll")                                                         \
            for (int n = 0; n < 4; n++)                                               \
                acc[m][n] = __builtin_amdgcn_mfma_f32_16x16x32_bf16(af[m], bfv[n], acc[m][n], 0, 0, 0); \
    }

template<int MODE, int BM, int BN>
__global__ __launch_bounds__(256) void gemm_bf16_kernel(const unsigned short* __restrict__ A,
                                                        const unsigned short* __restrict__ BT,
                                                        float* __restrict__ C,
                                                        unsigned short* __restrict__ outK,
                                                        unsigned short* __restrict__ outV,
                                                        int M, int N, int K,
                                                        const float* __restrict__ aux) {
    constexpr int NWC = BN / 64;          // col waves (1 or 2)
    constexpr int NWR = 4 / NWC;          // row waves
    constexpr int WROWS = BM / NWR;       // rows per wave
    constexpr int MREP = WROWS / 16;
    constexpr int EA = BM / 64;
    constexpr int EB = BN / 64;
    __shared__ __align__(16) unsigned short As0[BM * 32];
    __shared__ __align__(16) unsigned short As1[BM * 32];
    __shared__ __align__(16) unsigned short Bs0[BN * 32];
    __shared__ __align__(16) unsigned short Bs1[BN * 32];
    const int tid = threadIdx.x;
    const int l = tid & 63, w = tid >> 6;
    const int wr = w / NWC, wc = w % NWC;

    // T1: bijective XCD-chunked swizzle (nwg % 8 == 0)
    const int gx = gridDim.x;
    const int flat = blockIdx.y * gx + blockIdx.x;
    const int cpx = (gx * gridDim.y) >> 3;
    const int swz = (flat & 7) * cpx + (flat >> 3);
    const int rb = (swz / gx) * BM, cb = (swz % gx) * BN;

    f32x4 acc[MREP][4];
    #pragma unroll
    for (int m = 0; m < MREP; m++)
        #pragma unroll
        for (int n = 0; n < 4; n++) acc[m][n] = (f32x4){0.0f, 0.0f, 0.0f, 0.0f};

    const int srow = l >> 2;
    const int selt = (l & 3) * 8;
    const unsigned short* Ag = A + (size_t)rb * K;
    const unsigned short* Bg = BT + (size_t)cb * K;

    // 2-phase double-buffered K-loop (compile-time buffers)
    GEMM_STAGE(As0, Bs0, 0);
    __syncthreads();
    int kt = 0;
    for (; kt + 64 < K; kt += 64) {
        GEMM_STAGE(As1, Bs1, kt + 32);
        GEMM_COMPUTE(As0, Bs0);
        __syncthreads();
        GEMM_STAGE(As0, Bs0, kt + 64);
        GEMM_COMPUTE(As1, Bs1);
        __syncthreads();
    }
    GEMM_STAGE(As1, Bs1, kt + 32);
    GEMM_COMPUTE(As0, Bs0);
    __syncthreads();
    GEMM_COMPUTE(As1, Bs1);

    // C/D layout: col = lane&15 (+n*16), row = (lane>>4)*4 + r (+m*16)
    const int lx = l & 15;
    const int col0 = cb + wc * 64;
    const int row0 = rb + wr * WROWS + (l >> 4) * 4;

    if constexpr (MODE == 0) {
        #pragma unroll
        for (int m = 0; m < MREP; m++) {
            #pragma unroll
            for (int n = 0; n < 4; n++) {
                const int col = col0 + n * 16 + lx;
                const float badd = aux[col];
                #pragma unroll
                for (int r = 0; r < 4; r++)
                    C[(size_t)(row0 + m * 16 + r) * N + col] = acc[m][n][r] + badd;
            }
        }
    } else {
        const bool isK = (MODE == 2) || (col0 < (N >> 1));
        if (isK) {
            float g4[4];
            #pragma unroll
            for (int n = 0; n < 4; n++) g4[n] = aux[n * 16 + lx];
            const float fin = (MODE == 2) ? (0.125f * LOG2E) : 1.0f;
            #pragma unroll
            for (int m = 0; m < MREP; m++) {
                #pragma unroll
                for (int r = 0; r < 4; r++) {
                    float ss = 0.0f;
                    #pragma unroll
                    for (int n = 0; n < 4; n++) ss += acc[m][n][r] * acc[m][n][r];
                    ss += __shfl_xor(ss, 1);
                    ss += __shfl_xor(ss, 2);
                    ss += __shfl_xor(ss, 4);
                    ss += __shfl_xor(ss, 8);
                    const float inv = fin / fmaxf(sqrtf(ss) * 0.125f, 1e-8f);
                    const size_t rbase = (size_t)(row0 + m * 16 + r) * 1024 + col0;
                    #pragma unroll
                    for (int n = 0; n < 4; n++)
                        outK[rbase + n * 16 + lx] = f2bf(acc[m][n][r] * inv * g4[n]);
                }
            }
        } else {
            const int colv = col0 - 1024;
            #pragma unroll
            for (int m = 0; m < MREP; m++) {
                #pragma unroll
                for (int r = 0; r < 4; r++) {
                    const size_t rbase = (size_t)(row0 + m * 16 + r) * 1024 + colv;
                    #pragma unroll
                    for (int n = 0; n < 4; n++)
                        outV[rbase + n * 16 + lx] = f2bf(acc[m][n][r]);
                }
            }
        }
    }
}

// ---------------------------------------------------------------------------
// MFMA flash attention (exp2 domain), merged streams + 2 blocks/CU:
// 256 threads = 4 waves: sid = w>>1 (stream), wq = w&1 (16-row q-subtile);
// QBLK=32, grid (b*h=64, m/32=8) = 512 blocks. K/V staged once per block.
// T14 async-STAGE + double-buffered LDS, one barrier per kv-tile.
// Swapped QK^T; P->A-frag via register shuffles; T13 defer-max; T12 cvt_pk.
// qbh has SCALE*log2e folded in. K / V^T LDS tiles byte^=((row&7)<<4) swizzled.
// ---------------------------------------------------------------------------
__global__ __launch_bounds__(256) void attn_mfma_kernel(const unsigned short* __restrict__ qbh,
                                                        const unsigned short* __restrict__ kbh,
                                                        const unsigned short* __restrict__ vth,
                                                        const int* __restrict__ mask,
                                                        unsigned short* __restrict__ obuf) {
    const int bh = blockIdx.x;
    const int qt = blockIdx.y;               // 32-row q tile
    const int b = bh >> 4, h = bh & 15;
    const int tid = threadIdx.x;
    const int l = tid & 63, w = tid >> 6;    // 4 waves
    const int sid = w >> 1;                  // 0 = c1 (masked), 1 = c0
    const int wq = w & 1;                    // 16-row subtile within stream
    const int lq = l & 15, g = l >> 4;

    __shared__ __align__(16) unsigned short KVs[2][8192];  // [buf][ K 0..4095 | V^T 4096..8191 ]
    __shared__ int Ms[2][64];

    bf16x8 aq[2];
    const size_t qrow = (size_t)((sid * BB + b) * MM + qt * 32 + wq * 16 + lq);
    #pragma unroll
    for (int ks = 0; ks < 2; ks++)
        aq[ks] = *(const bf16x8*)&qbh[qrow * 1024 + h * 64 + ks * 32 + g * 8];

    // staging coords: 256 threads cover 64 rows x 8 col-chunks, 2 chunks each
    const int srow0 = tid >> 3, srow1 = (tid >> 3) + 32, sc8 = tid & 7;
    const unsigned short* kgb = kbh + (size_t)(b * NN) * 1024 + h * 64;
    const unsigned short* vgb = vth + ((size_t)(b * 16 + h) * 64) * 2048;
    bf16x8 kreg0, kreg1, vreg0, vreg1;
    int mreg = 0;

#define ATT_LOAD(t0)                                                                  \
    {                                                                                 \
        kreg0 = *(const bf16x8*)&kgb[(size_t)((t0) + srow0) * 1024 + sc8 * 8];        \
        kreg1 = *(const bf16x8*)&kgb[(size_t)((t0) + srow1) * 1024 + sc8 * 8];        \
        vreg0 = *(const bf16x8*)&vgb[(size_t)srow0 * 2048 + (t0) + sc8 * 8];          \
        vreg1 = *(const bf16x8*)&vgb[(size_t)srow1 * 2048 + (t0) + sc8 * 8];          \
        if (tid < 64) mreg = mask[b * NN + (t0) + tid];                               \
    }

#define ATT_WRITE(buf)                                                                \
    {                                                                                 \
        *(bf16x8*)&KVs[buf][srow0 * 64 + ((sc8 ^ (srow0 & 7)) * 8)] = kreg0;          \
        *(bf16x8*)&KVs[buf][srow1 * 64 + ((sc8 ^ (srow1 & 7)) * 8)] = kreg1;          \
        *(bf16x8*)&KVs[buf][4096 + srow0 * 64 + ((sc8 ^ (srow0 & 7)) * 8)] = vreg0;   \
        *(bf16x8*)&KVs[buf][4096 + srow1 * 64 + ((sc8 ^ (srow1 & 7)) * 8)] = vreg1;   \
        if (tid < 64) Ms[buf][tid] = mreg;                                            \
    }

    f32x4 oacc[4];
    #pragma unroll
    for (int n = 0; n < 4; n++) oacc[n] = (f32x4){0.0f, 0.0f, 0.0f, 0.0f};
    float mrun = -FLT_MAX, lrun = 0.0f;

    ATT_LOAD(0);
    ATT_WRITE(0);
    __syncthreads();
    int cur = 0;

    for (int t0 = 0; t0 < NN; t0 += 64) {
        const bool nxt = (t0 + 64 < NN);
        if (nxt) ATT_LOAD(t0 + 64);          // issue early: hides under compute

        const unsigned short* kcur = &KVs[cur][0];
        const unsigned short* vcur = &KVs[cur][4096];

        // S^T = K @ Q^T : st[j] holds S'[q=lq][kv = j*16 + g*4 + r] (log2 domain)
        f32x4 st[4];
        #pragma unroll
        for (int j = 0; j < 4; j++) st[j] = (f32x4){0.0f, 0.0f, 0.0f, 0.0f};
        #pragma unroll
        for (int j = 0; j < 4; j++) {
            #pragma unroll
            for (int ks = 0; ks < 2; ks++) {
                const int row = j * 16 + lq;
                const bf16x8 kf = *(const bf16x8*)&kcur[row * 64 + (((ks * 4 + g) ^ (row & 7)) * 8)];
                st[j] = __builtin_amdgcn_mfma_f32_16x16x32_bf16(kf, aq[ks], st[j], 0, 0, 0);
            }
        }

        float p[4][4];
        #pragma unroll
        for (int j = 0; j < 4; j++) {
            if (sid == 0) {
                const int4 mj = *(const int4*)&Ms[cur][j * 16 + g * 4];
                p[j][0] = mj.x ? st[j][0] : -3.0e38f;
                p[j][1] = mj.y ? st[j][1] : -3.0e38f;
                p[j][2] = mj.z ? st[j][2] : -3.0e38f;
                p[j][3] = mj.w ? st[j][3] : -3.0e38f;
            } else {
                #pragma unroll
                for (int r = 0; r < 4; r++) p[j][r] = st[j][r];
            }
        }

        float mloc = fmaxf(fmaxf(p[0][0], p[0][1]), fmaxf(p[0][2], p[0][3]));
        #pragma unroll
        for (int j = 1; j < 4; j++)
            mloc = fmaxf(mloc, fmaxf(fmaxf(p[j][0], p[j][1]), fmaxf(p[j][2], p[j][3])));
        mloc = fmaxf(mloc, __shfl_xor(mloc, 16));
        mloc = fmaxf(mloc, __shfl_xor(mloc, 32));

        // T13 defer-max (per-wave state)
        if (__any(mloc > mrun + 8.0f)) {
            const float mn = fmaxf(mrun, mloc);
            const float scal = fexp2(mrun - mn);
            mrun = mn;
            lrun *= scal;
            float oscal[4];
            #pragma unroll
            for (int r = 0; r < 4; r++) oscal[r] = __shfl(scal, g * 4 + r);
            #pragma unroll
            for (int n = 0; n < 4; n++)
                #pragma unroll
                for (int r = 0; r < 4; r++) oacc[n][r] *= oscal[r];
        }

        float rsum = 0.0f;
        #pragma unroll
        for (int j = 0; j < 4; j++)
            #pragma unroll
            for (int r = 0; r < 4; r++) { p[j][r] = fexp2(p[j][r] - mrun); rsum += p[j][r]; }
        rsum += __shfl_xor(rsum, 16);
        rsum += __shfl_xor(rsum, 32);
        lrun += rsum;

        // T12: pack P to bf16 pairs with v_cvt_pk_bf16_f32
        unsigned int packed[4][2];
        #pragma unroll
        for (int jt = 0; jt < 4; jt++)
            #pragma unroll
            for (int hh = 0; hh < 2; hh++)
                packed[jt][hh] = cvt_pk_bf16(p[jt][2 * hh], p[jt][2 * hh + 1]);

        #pragma unroll
        for (int ks = 0; ks < 2; ks++) {
            unsigned int wds[4];
            #pragma unroll
            for (int wd = 0; wd < 4; wd++) {
                const int src = lq + 16 * ((g & 1) * 2 + (wd >> 1));
                const unsigned int vA = (unsigned int)__shfl((int)packed[ks * 2][wd & 1], src);
                const unsigned int vB = (unsigned int)__shfl((int)packed[ks * 2 + 1][wd & 1], src);
                wds[wd] = (g & 2) ? vB : vA;
            }
            const u32x4 tmp = {wds[0], wds[1], wds[2], wds[3]};
            const bf16x8 afP = __builtin_bit_cast(bf16x8, tmp);
            #pragma unroll
            for (int n = 0; n < 4; n++) {
                const int drow = n * 16 + lq;
                const bf16x8 bv = *(const bf16x8*)&vcur[drow * 64 + (((ks * 4 + g) ^ (drow & 7)) * 8)];
                oacc[n] = __builtin_amdgcn_mfma_f32_16x16x32_bf16(afP, bv, oacc[n], 0, 0, 0);
            }
        }

        if (nxt) {
            ATT_WRITE(cur ^ 1);              // write late: after compute
            __syncthreads();                 // one barrier per tile
        }
        cur ^= 1;
    }

    const float il = 1.0f / lrun;
    float linv[4];
    #pragma unroll
    for (int r = 0; r < 4; r++) linv[r] = __shfl(il, g * 4 + r);
    unsigned short* ob = obuf + ((size_t)((sid * BB + b) * MM + qt * 32 + wq * 16)) * 1024 + h * 64;
    #pragma unroll
    for (int n = 0; n < 4; n++)
        #pragma unroll
        for (int r = 0; r < 4; r++)
            ob[(size_t)(g * 4 + r) * 1024 + n * 16 + lq] = f2bf(oacc[n][r] * linv[r]);
}

// ---------------------------------------------------------------------------
// Launch
// ---------------------------------------------------------------------------
extern "C" void kernel_launch(void* const* d_in, const int* in_sizes, int n_in,
                              void* d_out, int out_size, void* d_ws, size_t ws_size,
                              hipStream_t stream) {
    const float* x      = (const float*)d_in[0];
    const float* lc1    = (const float*)d_in[1];
    const float* lc0    = (const float*)d_in[2];
    const int*   mask   = (const int*)d_in[3];
    const float* ln_x_w = (const float*)d_in[4];
    const float* ln_x_b = (const float*)d_in[5];
    const float* ln_l_w = (const float*)d_in[6];
    const float* ln_l_b = (const float*)d_in[7];
    const float* g_q    = (const float*)d_in[8];
    const float* g_k    = (const float*)d_in[9];
    const float* Wq     = (const float*)d_in[10];
    const float* Wkv    = (const float*)d_in[11];
    const float* Wout   = (const float*)d_in[12];
    const float* bout   = (const float*)d_in[13];
    float* out = (float*)d_out;

    // workspace layout (all 16B-aligned)
    char* p = (char*)d_ws;
    unsigned short* xnb   = (unsigned short*)p; p += (size_t)8388608 * 2;   // 16 MB
    unsigned short* latb  = (unsigned short*)p; p += (size_t)2097152 * 2;   //  4 MB
    unsigned short* obb   = (unsigned short*)p; p += (size_t)2097152 * 2;   //  4 MB
    unsigned short* WkvT  = (unsigned short*)p; p += (size_t)2097152 * 2;   //  4 MB
    unsigned short* WqT   = (unsigned short*)p; p += (size_t)1048576 * 2;   //  2 MB
    unsigned short* WoutT = (unsigned short*)p; p += (size_t)1048576 * 2;   //  2 MB
    unsigned short* qbh   = (unsigned short*)p; p += (size_t)2097152 * 2;   //  4 MB
    unsigned short* kbh   = (unsigned short*)p; p += (size_t)8388608 * 2;   // 16 MB
    unsigned short* vbh   = (unsigned short*)p; p += (size_t)8388608 * 2;   // 16 MB
    unsigned short* vth   = (unsigned short*)p; p += (size_t)8388608 * 2;   // 16 MB

    // 1) All LayerNorms -> bf16 (one launch)
    ln_all_kernel<<<BB * NN + 2 * BB * MM, 256, 0, stream>>>(
        x, lc1, lc0, xnb, latb, ln_x_w, ln_x_b, ln_l_w, ln_l_b);

    // 2) All weight transpose-casts (one launch)
    transpose_all_kernel<<<dim3(64, 32, 3), 256, 0, stream>>>(
        Wkv, Wq, Wout, WkvT, WqT, WoutT);

    // 3) kv projection + fused K-RMS (MODE 1, 128x128): -> kbh, vbh bf16
    gemm_bf16_kernel<1, 128, 128><<<dim3(2048 / 128, 8192 / 128), 256, 0, stream>>>(
        xnb, WkvT, nullptr, kbh, vbh, 8192, 2048, 1024, g_k);
    // 4) q projection + fused Q-RMS*SCALE*log2e (MODE 2, 64x64 -> 512 blocks)
    gemm_bf16_kernel<2, 64, 64><<<dim3(1024 / 64, 2048 / 64), 256, 0, stream>>>(
        latb, WqT, nullptr, qbh, nullptr, 2048, 1024, 1024, g_q);

    // 5) V transpose (bf16)
    v_transpose_bf16<<<dim3(NN / 32, 2, BB * NHEADS), 256, 0, stream>>>(vbh, vth);

    // 6) MFMA attention (merged streams, QBLK=32, 2 blocks/CU) -> bf16 O
    attn_mfma_kernel<<<dim3(BB * NHEADS, MM / 32), 256, 0, stream>>>(qbh, kbh, vth, mask, obb);

    // 7) Output projection + bias -> d_out (MODE 0, 64x64 -> 512 blocks)
    gemm_bf16_kernel<0, 64, 64><<<dim3(1024 / 64, 2048 / 64), 256, 0, stream>>>(
        obb, WoutT, out, nullptr, nullptr, 2048, 1024, 1024, bout);
}

// Round 12
// 242.885 us; speedup vs baseline: 1.0474x; 1.0474x over previous
//
#include <hip/hip_runtime.h>
#include <hip/hip_bf16.h>
#include <float.h>
#include <math.h>

// Problem constants
#define BB 4
#define NN 2048
#define MM 256
#define DIN 1024
#define INNER 1024
#define NHEADS 16
#define DHEAD 64

typedef __attribute__((ext_vector_type(8))) short bf16x8;
typedef __attribute__((ext_vector_type(4))) float f32x4;
typedef __attribute__((ext_vector_type(4))) unsigned int u32x4;

// round-to-nearest-even f32 -> bf16 bit pattern
__device__ __forceinline__ unsigned short f2bf(float f) {
    unsigned int u = __builtin_bit_cast(unsigned int, f);
    u = (u + 0x7fffu + ((u >> 16) & 1u)) >> 16;
    return (unsigned short)u;
}

// raw v_exp_f32 (2^x)
__device__ __forceinline__ float fexp2(float x) {
#if __has_builtin(__builtin_amdgcn_exp2f)
    return __builtin_amdgcn_exp2f(x);
#else
    float r; asm("v_exp_f32 %0, %1" : "=v"(r) : "v"(x)); return r;
#endif
}

// v_cvt_pk_bf16_f32: lo16 = bf16(a), hi16 = bf16(b)  (T12 recipe)
__device__ __forceinline__ unsigned int cvt_pk_bf16(float a, float b) {
    unsigned int r;
    asm("v_cvt_pk_bf16_f32 %0, %1, %2" : "=v"(r) : "v"(a), "v"(b));
    return r;
}

// async global->LDS, 16B per lane; LDS dest = wave-uniform base.
__device__ __forceinline__ void gload_lds16(const void* g, void* l) {
    __builtin_amdgcn_global_load_lds((__attribute__((address_space(1))) void*)(g),
                                     (__attribute__((address_space(3))) void*)(l),
                                     16, 0, 0);
}

#define LOG2E 1.4426950408889634f

// ---------------------------------------------------------------------------
// Fused LayerNorm: rows [0,8192) = x -> xnb ; [8192,10240) = lc1|lc0 -> latb.
// ---------------------------------------------------------------------------
__global__ __launch_bounds__(256) void ln_all_kernel(const float* __restrict__ x,
                                                     const float* __restrict__ lc1,
                                                     const float* __restrict__ lc0,
                                                     unsigned short* __restrict__ xnb,
                                                     unsigned short* __restrict__ latb,
                                                     const float* __restrict__ xw,
                                                     const float* __restrict__ xb,
                                                     const float* __restrict__ lw,
                                                     const float* __restrict__ lb) {
    const int row = blockIdx.x;
    const float* srow;
    unsigned short* drow;
    const float *w, *bv;
    if (row < BB * NN) {
        srow = x + (size_t)row * 1024; drow = xnb + (size_t)row * 1024;
        w = xw; bv = xb;
    } else {
        const int r2 = row - BB * NN;
        srow = (r2 < BB * MM) ? (lc1 + (size_t)r2 * 1024)
                              : (lc0 + (size_t)(r2 - BB * MM) * 1024);
        drow = latb + (size_t)r2 * 1024;
        w = lw; bv = lb;
    }
    const int tid = threadIdx.x;
    const float4 v = ((const float4*)srow)[tid];
    float sum = v.x + v.y + v.z + v.w;
    float sq  = v.x * v.x + v.y * v.y + v.z * v.z + v.w * v.w;
    #pragma unroll
    for (int off = 32; off; off >>= 1) {
        sum += __shfl_down(sum, off);
        sq  += __shfl_down(sq, off);
    }
    __shared__ float ls[4], lq[4];
    const int wv = tid >> 6;
    if ((tid & 63) == 0) { ls[wv] = sum; lq[wv] = sq; }
    __syncthreads();
    sum = ls[0] + ls[1] + ls[2] + ls[3];
    sq  = lq[0] + lq[1] + lq[2] + lq[3];
    const float mu  = sum * (1.0f / 1024.0f);
    const float var = sq * (1.0f / 1024.0f) - mu * mu;
    const float rs  = rsqrtf(var + 1e-5f);
    const float4 w4 = ((const float4*)w)[tid];
    const float4 b4 = ((const float4*)bv)[tid];
    ushort4 o;
    o.x = f2bf((v.x - mu) * rs * w4.x + b4.x);
    o.y = f2bf((v.y - mu) * rs * w4.y + b4.y);
    o.z = f2bf((v.z - mu) * rs * w4.z + b4.z);
    o.w = f2bf((v.w - mu) * rs * w4.w + b4.w);
    ((ushort4*)drow)[tid] = o;
}

// ---------------------------------------------------------------------------
// Fused weight transpose + cast: z=0 Wkv(1024x2048), z=1 Wq, z=2 Wout.
// ---------------------------------------------------------------------------
__global__ __launch_bounds__(256) void transpose_all_kernel(const float* __restrict__ Wkv,
                                                            const float* __restrict__ Wq,
                                                            const float* __restrict__ Wout,
                                                            unsigned short* __restrict__ WkvT,
                                                            unsigned short* __restrict__ WqT,
                                                            unsigned short* __restrict__ WoutT) {
    const int z = blockIdx.z;
    const float* W;
    unsigned short* WT;
    int N;
    if (z == 0)      { W = Wkv;  WT = WkvT;  N = 2048; }
    else if (z == 1) { W = Wq;   WT = WqT;   N = 1024; }
    else             { W = Wout; WT = WoutT; N = 1024; }
    if (blockIdx.x * 32 >= N) return;
    const int K = 1024;
    __shared__ float t[32][33];
    const int k0 = blockIdx.y * 32, n0 = blockIdx.x * 32;
    const int tx = threadIdx.x & 31, ty8 = threadIdx.x >> 5;
    #pragma unroll
    for (int i = 0; i < 4; i++) {
        const int k = ty8 + i * 8;
        t[k][tx] = W[(size_t)(k0 + k) * N + n0 + tx];
    }
    __syncthreads();
    #pragma unroll
    for (int i = 0; i < 4; i++) {
        const int n = ty8 + i * 8;
        WT[(size_t)(n0 + n) * K + k0 + tx] = f2bf(t[tx][n]);
    }
}

// ---------------------------------------------------------------------------
// V transpose (bf16->bf16): vbh[b*N+n][h*64+d] -> vth[(b*16+h)*64+d][n (2048)]
// ---------------------------------------------------------------------------
__global__ __launch_bounds__(256) void v_transpose_bf16(const unsigned short* __restrict__ vbh,
                                                        unsigned short* __restrict__ vth) {
    __shared__ unsigned short t[32][34];
    const int n0 = blockIdx.x * 32;
    const int d0 = blockIdx.y * 32;
    const int bh = blockIdx.z;
    const int b = bh >> 4, h = bh & 15;
    const int tx = threadIdx.x & 31, ty8 = threadIdx.x >> 5;
    #pragma unroll
    for (int i = 0; i < 4; i++) {
        const int nr = ty8 + i * 8;
        t[nr][tx] = vbh[(size_t)(b * NN + n0 + nr) * 1024 + h * 64 + d0 + tx];
    }
    __syncthreads();
    #pragma unroll
    for (int i = 0; i < 4; i++) {
        const int dr = ty8 + i * 8;
        vth[((size_t)(b * 16 + h) * 64 + d0 + dr) * 2048 + n0 + tx] = t[tx][dr];
    }
}

// ---------------------------------------------------------------------------
// bf16 MFMA GEMM, BMxBN tile, BK=32, double-buffered 2-phase, XCD-swizzled.
// MODE 0: C f32 (+bias aux).
// MODE 1: kv -> K half rms-normed*gamma_k -> outK bf16 ; V half -> outV bf16.
// MODE 2: q  -> rms-normed*gamma_q*SCALE*log2e -> outK bf16.
// ---------------------------------------------------------------------------
#define GEMM_STAGE(AS, BS, kt)                                                        \
    {                                                                                 \
        _Pragma("unroll")                                                             \
        for (int e = 0; e < EA; e++) {                                                \
            const int r0 = (w * EA + e) * 16;                                         \
            gload_lds16(Ag + (size_t)(r0 + srow) * K + (kt) + selt, &AS[r0 * 32]);    \
        }                                                                             \
        _Pragma("unroll")                                                             \
        for (int e = 0; e < EB; e++) {                                                \
            const int r0 = (w * EB + e) * 16;                                         \
            gload_lds16(Bg + (size_t)(r0 + srow) * K + (kt) + selt, &BS[r0 * 32]);    \
        }                                                                             \
    }

#define GEMM_COMPUTE(AS, BS)                                                          \
    {                                                                                 \
        bf16x8 af[MREP], bfv[4];                                                      \
        _Pragma("unroll")                                                             \
        for (int m = 0; m < MREP; m++)                                                \
            af[m] = *(const bf16x8*)&AS[(wr * WROWS + m * 16 + (l & 15)) * 32 + (l >> 4) * 8]; \
        _Pragma("unroll")                                                             \
        for (int n = 0; n < 4; n++)                                                   \
            bfv[n] = *(const bf16x8*)&BS[(wc * 64 + n * 16 + (l & 15)) * 32 + (l >> 4) * 8]; \
        _Pragma("unroll")                                                             \
        for (int m = 0; m < MREP; m++)                                                \
            _Pragma("unroll")                                                         \
            for (int n = 0; n < 4; n++)                                               \
                acc[m][n] = __builtin_amdgcn_mfma_f32_16x16x32_bf16(af[m], bfv[n], acc[m][n], 0, 0, 0); \
    }

template<int MODE, int BM, int BN>
__global__ __launch_bounds__(256) void gemm_bf16_kernel(const unsigned short* __restrict__ A,
                                                        const unsigned short* __restrict__ BT,
                                                        float* __restrict__ C,
                                                        unsigned short* __restrict__ outK,
                                                        unsigned short* __restrict__ outV,
                                                        int M, int N, int K,
                                                        const float* __restrict__ aux) {
    constexpr int NWC = BN / 64;
    constexpr int NWR = 4 / NWC;
    constexpr int WROWS = BM / NWR;
    constexpr int MREP = WROWS / 16;
    constexpr int EA = BM / 64;
    constexpr int EB = BN / 64;
    __shared__ __align__(16) unsigned short As0[BM * 32];
    __shared__ __align__(16) unsigned short As1[BM * 32];
    __shared__ __align__(16) unsigned short Bs0[BN * 32];
    __shared__ __align__(16) unsigned short Bs1[BN * 32];
    const int tid = threadIdx.x;
    const int l = tid & 63, w = tid >> 6;
    const int wr = w / NWC, wc = w % NWC;

    // T1: bijective XCD-chunked swizzle (nwg % 8 == 0)
    const int gx = gridDim.x;
    const int flat = blockIdx.y * gx + blockIdx.x;
    const int cpx = (gx * gridDim.y) >> 3;
    const int swz = (flat & 7) * cpx + (flat >> 3);
    const int rb = (swz / gx) * BM, cb = (swz % gx) * BN;

    f32x4 acc[MREP][4];
    #pragma unroll
    for (int m = 0; m < MREP; m++)
        #pragma unroll
        for (int n = 0; n < 4; n++) acc[m][n] = (f32x4){0.0f, 0.0f, 0.0f, 0.0f};

    const int srow = l >> 2;
    const int selt = (l & 3) * 8;
    const unsigned short* Ag = A + (size_t)rb * K;
    const unsigned short* Bg = BT + (size_t)cb * K;

    GEMM_STAGE(As0, Bs0, 0);
    __syncthreads();
    int kt = 0;
    for (; kt + 64 < K; kt += 64) {
        GEMM_STAGE(As1, Bs1, kt + 32);
        GEMM_COMPUTE(As0, Bs0);
        __syncthreads();
        GEMM_STAGE(As0, Bs0, kt + 64);
        GEMM_COMPUTE(As1, Bs1);
        __syncthreads();
    }
    GEMM_STAGE(As1, Bs1, kt + 32);
    GEMM_COMPUTE(As0, Bs0);
    __syncthreads();
    GEMM_COMPUTE(As1, Bs1);

    // C/D layout: col = lane&15 (+n*16), row = (lane>>4)*4 + r (+m*16)
    const int lx = l & 15;
    const int col0 = cb + wc * 64;
    const int row0 = rb + wr * WROWS + (l >> 4) * 4;

    if constexpr (MODE == 0) {
        #pragma unroll
        for (int m = 0; m < MREP; m++) {
            #pragma unroll
            for (int n = 0; n < 4; n++) {
                const int col = col0 + n * 16 + lx;
                const float badd = aux[col];
                #pragma unroll
                for (int r = 0; r < 4; r++)
                    C[(size_t)(row0 + m * 16 + r) * N + col] = acc[m][n][r] + badd;
            }
        }
    } else {
        const bool isK = (MODE == 2) || (col0 < (N >> 1));
        if (isK) {
            float g4[4];
            #pragma unroll
            for (int n = 0; n < 4; n++) g4[n] = aux[n * 16 + lx];
            const float fin = (MODE == 2) ? (0.125f * LOG2E) : 1.0f;
            #pragma unroll
            for (int m = 0; m < MREP; m++) {
                #pragma unroll
                for (int r = 0; r < 4; r++) {
                    float ss = 0.0f;
                    #pragma unroll
                    for (int n = 0; n < 4; n++) ss += acc[m][n][r] * acc[m][n][r];
                    ss += __shfl_xor(ss, 1);
                    ss += __shfl_xor(ss, 2);
                    ss += __shfl_xor(ss, 4);
                    ss += __shfl_xor(ss, 8);
                    const float inv = fin / fmaxf(sqrtf(ss) * 0.125f, 1e-8f);
                    const size_t rbase = (size_t)(row0 + m * 16 + r) * 1024 + col0;
                    #pragma unroll
                    for (int n = 0; n < 4; n++)
                        outK[rbase + n * 16 + lx] = f2bf(acc[m][n][r] * inv * g4[n]);
                }
            }
        } else {
            const int colv = col0 - 1024;
            #pragma unroll
            for (int m = 0; m < MREP; m++) {
                #pragma unroll
                for (int r = 0; r < 4; r++) {
                    const size_t rbase = (size_t)(row0 + m * 16 + r) * 1024 + colv;
                    #pragma unroll
                    for (int n = 0; n < 4; n++)
                        outV[rbase + n * 16 + lx] = f2bf(acc[m][n][r]);
                }
            }
        }
    }
}

// ---------------------------------------------------------------------------
// MFMA flash attention, NO-MAX softmax (S' bounded: |S'| <= ~12 in log2 domain,
// exp2 sums < 1e7 -- f32-safe with m=0 fixed; masked fill -3e38 -> exp2 -> 0).
// Merged streams, 8 waves / 512 thr: waves 0-3 = c1 (masked), 4-7 = c0.
// QBLK=64, grid (b*h=64, m/64=4). K/V staged once per block; T14 async-STAGE
// + double-buffered LDS, one barrier per kv-tile. Swapped QK^T; P->A-frag via
// register shuffles; T12 cvt_pk. qbh has SCALE*log2e folded in.
// K / V^T LDS tiles byte^=((row&7)<<4) swizzled.
// ---------------------------------------------------------------------------
__global__ __launch_bounds__(512) void attn_mfma_kernel(const unsigned short* __restrict__ qbh,
                                                        const unsigned short* __restrict__ kbh,
                                                        const unsigned short* __restrict__ vth,
                                                        const int* __restrict__ mask,
                                                        unsigned short* __restrict__ obuf) {
    const int bh = blockIdx.x;
    const int qt = blockIdx.y;
    const int b = bh >> 4, h = bh & 15;
    const int tid = threadIdx.x;
    const int l = tid & 63, w = tid >> 6;     // 8 waves
    const int sid = w >> 2;                    // 0 = c1 (masked), 1 = c0
    const int wq = w & 3;                      // 16-row q subtile within stream
    const int lq = l & 15, g = l >> 4;

    __shared__ __align__(16) unsigned short KVs[2][8192];  // [buf][ K 0..4095 | V^T 4096..8191 ]
    __shared__ int Ms[2][64];

    bf16x8 aq[2];
    const size_t qrow = (size_t)((sid * BB + b) * MM + qt * 64 + wq * 16 + lq);
    #pragma unroll
    for (int ks = 0; ks < 2; ks++)
        aq[ks] = *(const bf16x8*)&qbh[qrow * 1024 + h * 64 + ks * 32 + g * 8];

    // staging coords: 512 threads cover 64 rows x 8 col-chunks, one K + one V each
    const int srow = tid >> 3, sc8 = tid & 7;
    const unsigned short* kgb = kbh + (size_t)(b * NN) * 1024 + h * 64;
    const unsigned short* vgb = vth + ((size_t)(b * 16 + h) * 64) * 2048;
    bf16x8 kreg, vreg;
    int mreg = 0;

#define ATT_LOAD(t0)                                                                  \
    {                                                                                 \
        kreg = *(const bf16x8*)&kgb[(size_t)((t0) + srow) * 1024 + sc8 * 8];          \
        vreg = *(const bf16x8*)&vgb[(size_t)srow * 2048 + (t0) + sc8 * 8];            \
        if (tid < 64) mreg = mask[b * NN + (t0) + tid];                               \
    }

#define ATT_WRITE(buf)                                                                \
    {                                                                                 \
        *(bf16x8*)&KVs[buf][srow * 64 + ((sc8 ^ (srow & 7)) * 8)] = kreg;             \
        *(bf16x8*)&KVs[buf][4096 + srow * 64 + ((sc8 ^ (srow & 7)) * 8)] = vreg;      \
        if (tid < 64) Ms[buf][tid] = mreg;                                            \
    }

    f32x4 oacc[4];
    #pragma unroll
    for (int n = 0; n < 4; n++) oacc[n] = (f32x4){0.0f, 0.0f, 0.0f, 0.0f};
    float lrun = 0.0f;                         // per-lane partial; reduced once at end

    ATT_LOAD(0);
    ATT_WRITE(0);
    __syncthreads();
    int cur = 0;

    for (int t0 = 0; t0 < NN; t0 += 64) {
        const bool nxt = (t0 + 64 < NN);
        if (nxt) ATT_LOAD(t0 + 64);          // issue early: hides under compute

        const unsigned short* kcur = &KVs[cur][0];
        const unsigned short* vcur = &KVs[cur][4096];

        // S^T = K @ Q^T : st[j] holds S'[q=lq][kv = j*16 + g*4 + r] (log2 domain)
        f32x4 st[4];
        #pragma unroll
        for (int j = 0; j < 4; j++) st[j] = (f32x4){0.0f, 0.0f, 0.0f, 0.0f};
        #pragma unroll
        for (int j = 0; j < 4; j++) {
            #pragma unroll
            for (int ks = 0; ks < 2; ks++) {
                const int row = j * 16 + lq;
                const bf16x8 kf = *(const bf16x8*)&kcur[row * 64 + (((ks * 4 + g) ^ (row & 7)) * 8)];
                st[j] = __builtin_amdgcn_mfma_f32_16x16x32_bf16(kf, aq[ks], st[j], 0, 0, 0);
            }
        }

        // no-max softmax: p = exp2(S') directly; masked -> exp2(-3e38) = 0
        float p[4][4];
        #pragma unroll
        for (int j = 0; j < 4; j++) {
            if (sid == 0) {
                const int4 mj = *(const int4*)&Ms[cur][j * 16 + g * 4];
                p[j][0] = fexp2(mj.x ? st[j][0] : -3.0e38f);
                p[j][1] = fexp2(mj.y ? st[j][1] : -3.0e38f);
                p[j][2] = fexp2(mj.z ? st[j][2] : -3.0e38f);
                p[j][3] = fexp2(mj.w ? st[j][3] : -3.0e38f);
            } else {
                #pragma unroll
                for (int r = 0; r < 4; r++) p[j][r] = fexp2(st[j][r]);
            }
            lrun += p[j][0] + p[j][1] + p[j][2] + p[j][3];
        }

        // T12: pack P to bf16 pairs with v_cvt_pk_bf16_f32
        unsigned int packed[4][2];
        #pragma unroll
        for (int jt = 0; jt < 4; jt++)
            #pragma unroll
            for (int hh = 0; hh < 2; hh++)
                packed[jt][hh] = cvt_pk_bf16(p[jt][2 * hh], p[jt][2 * hh + 1]);

        #pragma unroll
        for (int ks = 0; ks < 2; ks++) {
            unsigned int wds[4];
            #pragma unroll
            for (int wd = 0; wd < 4; wd++) {
                const int src = lq + 16 * ((g & 1) * 2 + (wd >> 1));
                const unsigned int vA = (unsigned int)__shfl((int)packed[ks * 2][wd & 1], src);
                const unsigned int vB = (unsigned int)__shfl((int)packed[ks * 2 + 1][wd & 1], src);
                wds[wd] = (g & 2) ? vB : vA;
            }
            const u32x4 tmp = {wds[0], wds[1], wds[2], wds[3]};
            const bf16x8 afP = __builtin_bit_cast(bf16x8, tmp);
            #pragma unroll
            for (int n = 0; n < 4; n++) {
                const int drow = n * 16 + lq;
                const bf16x8 bv = *(const bf16x8*)&vcur[drow * 64 + (((ks * 4 + g) ^ (drow & 7)) * 8)];
                oacc[n] = __builtin_amdgcn_mfma_f32_16x16x32_bf16(afP, bv, oacc[n], 0, 0, 0);
            }
        }

        if (nxt) {
            ATT_WRITE(cur ^ 1);              // write late: after compute
            __syncthreads();                 // one barrier per tile
        }
        cur ^= 1;
    }

    // single end-of-loop l reduction over g-groups
    lrun += __shfl_xor(lrun, 16);
    lrun += __shfl_xor(lrun, 32);
    const float il = 1.0f / lrun;
    float linv[4];
    #pragma unroll
    for (int r = 0; r < 4; r++) linv[r] = __shfl(il, g * 4 + r);
    unsigned short* ob = obuf + ((size_t)((sid * BB + b) * MM + qt * 64 + wq * 16)) * 1024 + h * 64;
    #pragma unroll
    for (int n = 0; n < 4; n++)
        #pragma unroll
        for (int r = 0; r < 4; r++)
            ob[(size_t)(g * 4 + r) * 1024 + n * 16 + lq] = f2bf(oacc[n][r] * linv[r]);
}

// ---------------------------------------------------------------------------
// Launch
// ---------------------------------------------------------------------------
extern "C" void kernel_launch(void* const* d_in, const int* in_sizes, int n_in,
                              void* d_out, int out_size, void* d_ws, size_t ws_size,
                              hipStream_t stream) {
    const float* x      = (const float*)d_in[0];
    const float* lc1    = (const float*)d_in[1];
    const float* lc0    = (const float*)d_in[2];
    const int*   mask   = (const int*)d_in[3];
    const float* ln_x_w = (const float*)d_in[4];
    const float* ln_x_b = (const float*)d_in[5];
    const float* ln_l_w = (const float*)d_in[6];
    const float* ln_l_b = (const float*)d_in[7];
    const float* g_q    = (const float*)d_in[8];
    const float* g_k    = (const float*)d_in[9];
    const float* Wq     = (const float*)d_in[10];
    const float* Wkv    = (const float*)d_in[11];
    const float* Wout   = (const float*)d_in[12];
    const float* bout   = (const float*)d_in[13];
    float* out = (float*)d_out;

    // workspace layout (all 16B-aligned)
    char* p = (char*)d_ws;
    unsigned short* xnb   = (unsigned short*)p; p += (size_t)8388608 * 2;   // 16 MB
    unsigned short* latb  = (unsigned short*)p; p += (size_t)2097152 * 2;   //  4 MB
    unsigned short* obb   = (unsigned short*)p; p += (size_t)2097152 * 2;   //  4 MB
    unsigned short* WkvT  = (unsigned short*)p; p += (size_t)2097152 * 2;   //  4 MB
    unsigned short* WqT   = (unsigned short*)p; p += (size_t)1048576 * 2;   //  2 MB
    unsigned short* WoutT = (unsigned short*)p; p += (size_t)1048576 * 2;   //  2 MB
    unsigned short* qbh   = (unsigned short*)p; p += (size_t)2097152 * 2;   //  4 MB
    unsigned short* kbh   = (unsigned short*)p; p += (size_t)8388608 * 2;   // 16 MB
    unsigned short* vbh   = (unsigned short*)p; p += (size_t)8388608 * 2;   // 16 MB
    unsigned short* vth   = (unsigned short*)p; p += (size_t)8388608 * 2;   // 16 MB

    // 1) All LayerNorms -> bf16 (one launch)
    ln_all_kernel<<<BB * NN + 2 * BB * MM, 256, 0, stream>>>(
        x, lc1, lc0, xnb, latb, ln_x_w, ln_x_b, ln_l_w, ln_l_b);

    // 2) All weight transpose-casts (one launch)
    transpose_all_kernel<<<dim3(64, 32, 3), 256, 0, stream>>>(
        Wkv, Wq, Wout, WkvT, WqT, WoutT);

    // 3) kv projection + fused K-RMS (MODE 1, 128x128): -> kbh, vbh bf16
    gemm_bf16_kernel<1, 128, 128><<<dim3(2048 / 128, 8192 / 128), 256, 0, stream>>>(
        xnb, WkvT, nullptr, kbh, vbh, 8192, 2048, 1024, g_k);
    // 4) q projection + fused Q-RMS*SCALE*log2e (MODE 2, 64x64 -> 512 blocks)
    gemm_bf16_kernel<2, 64, 64><<<dim3(1024 / 64, 2048 / 64), 256, 0, stream>>>(
        latb, WqT, nullptr, qbh, nullptr, 2048, 1024, 1024, g_q);

    // 5) V transpose (bf16)
    v_transpose_bf16<<<dim3(NN / 32, 2, BB * NHEADS), 256, 0, stream>>>(vbh, vth);

    // 6) MFMA attention (merged streams, QBLK=64, no-max softmax) -> bf16 O
    attn_mfma_kernel<<<dim3(BB * NHEADS, MM / 64), 512, 0, stream>>>(qbh, kbh, vth, mask, obb);

    // 7) Output projection + bias -> d_out (MODE 0, 64x64 -> 512 blocks)
    gemm_bf16_kernel<0, 64, 64><<<dim3(1024 / 64, 2048 / 64), 256, 0, stream>>>(
        obb, WoutT, out, nullptr, nullptr, 2048, 1024, 1024, bout);
}